// Round 8
// baseline (174.919 us; speedup 1.0000x reference)
//
#include <hip/hip_runtime.h>
#include <cstdint>

// Problem constants: B=32, C=256, P=32, H=W=56
#define B_    32
#define C_    256
#define P_    32
#define HW_   3136
#define NSTEP 98          // k-steps of 32 (98*32 = 3136)

typedef __attribute__((ext_vector_type(8))) short  short8;   // 8 x bf16 (MFMA A/B frag)
typedef __attribute__((ext_vector_type(4))) float  floatx4;  // MFMA C/D frag

__device__ __forceinline__ unsigned short f2bf(float f) {
    // round-to-nearest-even f32 -> bf16
    union { float f; unsigned u; } v; v.f = f;
    unsigned r = v.u + 0x7fffu + ((v.u >> 16) & 1u);
    return (unsigned short)(r >> 16);
}

// ---------------------------------------------------------------------------
// Kernel 1: wpart[b,p,hw] = bf16( part[b,p,hw] * sigmoid(sum_p' part*w + b) )
// Two passes over p per thread (2nd pass L1/L2-hot). ~4-5 us.
// ---------------------------------------------------------------------------
__global__ __launch_bounds__(64) void wprep_kernel(
    const float* __restrict__ part, const float* __restrict__ conv_w,
    const float* __restrict__ conv_b, unsigned short* __restrict__ wpart)
{
    const int HW4 = HW_ / 4;                          // 784
    int i4 = blockIdx.x * 64 + threadIdx.x;           // over B*HW/4 = 25088
    if (i4 >= B_ * HW4) return;
    int b  = i4 / HW4;
    int hw = (i4 - b * HW4) * 4;

    const float* pb = part + (size_t)b * P_ * HW_ + hw;
    float bias = conv_b[0];
    float4 z = make_float4(bias, bias, bias, bias);
#pragma unroll
    for (int p = 0; p < P_; ++p) {
        float w = conv_w[p];
        float4 v = *(const float4*)(pb + (size_t)p * HW_);
        z.x += v.x * w; z.y += v.y * w; z.z += v.z * w; z.w += v.w * w;
    }
    float4 a;
    a.x = 1.0f / (1.0f + __expf(-z.x));
    a.y = 1.0f / (1.0f + __expf(-z.y));
    a.z = 1.0f / (1.0f + __expf(-z.z));
    a.w = 1.0f / (1.0f + __expf(-z.w));

    unsigned short* ob = wpart + (size_t)b * P_ * HW_ + hw;
#pragma unroll
    for (int p = 0; p < P_; ++p) {
        float4 v = *(const float4*)(pb + (size_t)p * HW_);   // L1/L2-hot reload
        ushort4 o;
        o.x = f2bf(v.x * a.x); o.y = f2bf(v.y * a.y);
        o.z = f2bf(v.z * a.z); o.w = f2bf(v.w * a.w);
        *(ushort4*)(ob + (size_t)p * HW_) = o;
    }
}

// ---------------------------------------------------------------------------
// Kernel 2: barrier-free streaming bf16-MFMA GEMM, v3: MANUAL ROTATING
// SOFTWARE PIPELINE (cur/nxt).  feats[b,p,c] = sum_k wpart[b,p,k]*x[b,c,k]
// Grid = (8 c-chunks, 32 b) = 256 blocks x 512 thr -> 8 waves/CU.
// Wave w owns k-slice [w*98/8,(w+1)*98/8). Per step: issue NEXT step's 6
// global loads first, then cvt+4 MFMA on CURRENT regs, then rotate. The
// waitcnt before the cvt only needs the older load group (vmcnt never
// drains to 0 - AITER pattern), so >=6KB/wave stays in flight continuously.
// No LDS operands, no barriers in the K-loop.
// Epilogue: single LDS reduce over the 8 k-slice waves, plain stores.
// ---------------------------------------------------------------------------
__global__ __launch_bounds__(512, 2) void gemm_stream3(
    const float* __restrict__ x,              // [B,C,HW] fp32
    const unsigned short* __restrict__ wpart, // [B,P,HW] bf16
    float* __restrict__ out)                  // [B, P*C]
{
    __shared__ float red[8][1024];            // 32 KB

    const int ct = blockIdx.x;                // c-chunk 0..7
    const int b  = blockIdx.y;                // batch
    const int c0 = ct * 32;

    const int tid  = threadIdx.x;
    const int wv   = tid >> 6;                // 0..7 : k-slice
    const int lane = tid & 63;
    const int qd   = lane >> 4;               // quad 0..3 -> k-offset qd*8
    const int r15  = lane & 15;               // row within 16

    const int t0 = wv * NSTEP / 8;
    const int t1 = (wv + 1) * NSTEP / 8;

    // lane-fixed base pointers (k advances by 32 floats per step)
    const float*          xr0 = x + (size_t)b * C_ * HW_ + (size_t)(c0 + r15) * HW_ + qd * 8;
    const float*          xr1 = xr0 + (size_t)16 * HW_;
    const unsigned short* ar0 = wpart + (size_t)b * P_ * HW_ + (size_t)r15 * HW_ + qd * 8;
    const unsigned short* ar1 = ar0 + (size_t)16 * HW_;

    floatx4 acc00 = (floatx4)0.0f, acc01 = (floatx4)0.0f;
    floatx4 acc10 = (floatx4)0.0f, acc11 = (floatx4)0.0f;

    // ---- pipeline prologue: load step t0 into cur ----
    int kb = t0 * 32;
    short8 a0c = *(const short8*)(ar0 + kb);
    short8 a1c = *(const short8*)(ar1 + kb);
    float4 x00c = *(const float4*)(xr0 + kb);
    float4 x01c = *(const float4*)(xr0 + kb + 4);
    float4 x10c = *(const float4*)(xr1 + kb);
    float4 x11c = *(const float4*)(xr1 + kb + 4);

    for (int t = t0; t < t1; ++t) {
        // ---- issue NEXT step's loads first (clamped on last iter; harmless) ----
        const int kn = ((t + 1 < t1) ? (t + 1) : t) * 32;
        short8 a0n = *(const short8*)(ar0 + kn);
        short8 a1n = *(const short8*)(ar1 + kn);
        float4 x00n = *(const float4*)(xr0 + kn);
        float4 x01n = *(const float4*)(xr0 + kn + 4);
        float4 x10n = *(const float4*)(xr1 + kn);
        float4 x11n = *(const float4*)(xr1 + kn + 4);

        // ---- consume CURRENT step ----
        short8 b0, b1;
        b0[0] = (short)f2bf(x00c.x); b0[1] = (short)f2bf(x00c.y);
        b0[2] = (short)f2bf(x00c.z); b0[3] = (short)f2bf(x00c.w);
        b0[4] = (short)f2bf(x01c.x); b0[5] = (short)f2bf(x01c.y);
        b0[6] = (short)f2bf(x01c.z); b0[7] = (short)f2bf(x01c.w);
        b1[0] = (short)f2bf(x10c.x); b1[1] = (short)f2bf(x10c.y);
        b1[2] = (short)f2bf(x10c.z); b1[3] = (short)f2bf(x10c.w);
        b1[4] = (short)f2bf(x11c.x); b1[5] = (short)f2bf(x11c.y);
        b1[6] = (short)f2bf(x11c.z); b1[7] = (short)f2bf(x11c.w);

        acc00 = __builtin_amdgcn_mfma_f32_16x16x32_bf16(a0c, b0, acc00, 0, 0, 0);
        acc01 = __builtin_amdgcn_mfma_f32_16x16x32_bf16(a0c, b1, acc01, 0, 0, 0);
        acc10 = __builtin_amdgcn_mfma_f32_16x16x32_bf16(a1c, b0, acc10, 0, 0, 0);
        acc11 = __builtin_amdgcn_mfma_f32_16x16x32_bf16(a1c, b1, acc11, 0, 0, 0);

        // ---- rotate ----
        a0c = a0n; a1c = a1n;
        x00c = x00n; x01c = x01n; x10c = x10n; x11c = x11n;
    }

    // ---- reduction across the 8 k-slice waves ----
    // D layout: m = a*16 + qd*4 + rg, n = g*16 + r15 ; local idx = m*32 + n
#pragma unroll
    for (int rg = 0; rg < 4; ++rg) {
        red[wv][(qd * 4 + rg) * 32 + r15]            = acc00[rg];
        red[wv][(qd * 4 + rg) * 32 + 16 + r15]       = acc01[rg];
        red[wv][(16 + qd * 4 + rg) * 32 + r15]       = acc10[rg];
        red[wv][(16 + qd * 4 + rg) * 32 + 16 + r15]  = acc11[rg];
    }
    __syncthreads();

#pragma unroll
    for (int h = 0; h < 2; ++h) {
        int idx = h * 512 + tid;              // 0..1023
        float s = 0.0f;
#pragma unroll
        for (int w = 0; w < 8; ++w) s += red[w][idx];
        int p  = idx >> 5;                    // 0..31
        int cl = idx & 31;                    // 0..31
        out[(size_t)b * (P_ * C_) + p * C_ + c0 + cl] = s;
    }
}

extern "C" void kernel_launch(void* const* d_in, const int* in_sizes, int n_in,
                              void* d_out, int out_size, void* d_ws, size_t ws_size,
                              hipStream_t stream) {
    const float* x      = (const float*)d_in[0];
    const float* part   = (const float*)d_in[1];
    const float* conv_w = (const float*)d_in[2];
    const float* conv_b = (const float*)d_in[3];
    unsigned short* wpart = (unsigned short*)d_ws;   // [B,P,HW] bf16 = 6.4 MB

    wprep_kernel<<<dim3((B_ * (HW_ / 4) + 63) / 64), dim3(64), 0, stream>>>(
        part, conv_w, conv_b, wpart);

    gemm_stream3<<<dim3(8, B_), dim3(512), 0, stream>>>(
        x, wpart, (float*)d_out);
}